// Round 12
// baseline (409.011 us; speedup 1.0000x reference)
//
#include <hip/hip_runtime.h>
#include <hip/hip_bf16.h>

// Problem constants
#define NB 8
#define NL 2500
#define ND 512
#define NY 8921

// Tiling
#define BM 256             // G rows per block (128 labels, U/W interleaved)
#define BN 256             // l-tile
#define BK 32              // k-slice per LDS tile (2 tiles per K-tile of 64)
#define NKS 16             // slices per l-tile
#define LPAD 2560          // 10 * 256
#define NLT 10             // LPAD/BN
#define NYB 70             // ceil(NY/128)
#define YPAD 8960          // NYB*128

#define SPLIT 5            // l-range splits (2 l-tiles per block)
#define LSPL_MAIN 2

#define TILE 16384         // 256 rows x 32 bf16 (64B/row), row-pair swizzled image
#define GT_BYTES ((size_t)NYB * NKS * TILE)              // 18,350,080
#define XT_BYTES ((size_t)NB * NLT * NKS * TILE)         // 20,971,520
#define P_ELEMS  ((size_t)SPLIT * NB * YPAD)             // 358,400
#define P_BYTES  (P_ELEMS * 4)

typedef short s8v  __attribute__((ext_vector_type(8)));
typedef float f16v __attribute__((ext_vector_type(16)));

__device__ __forceinline__ unsigned short f2bf(float f) {
  unsigned int u = __float_as_uint(f);
  return (unsigned short)((u + 0x7FFFu + ((u >> 16) & 1u)) >> 16);
}
__device__ __forceinline__ unsigned int pk2(float a, float b) {
  return (unsigned int)f2bf(a) | ((unsigned int)f2bf(b) << 16);
}
__device__ __forceinline__ void async_copy16(const char* g, char* l) {
  __builtin_amdgcn_global_load_lds(
      (const __attribute__((address_space(1))) void*)g,
      (__attribute__((address_space(3))) void*)l, 16, 0, 0);
}

// Swizzled tile byte offset for (row r in [0,256), 16B-granule gn in [0,4)):
// row-pair rp=r>>1 owns a 128B line; within-line = ((r&1)*64 + gn*16) ^ ((rp&7)<<4)
__device__ __forceinline__ int tile_off(int r, int gn) {
  int rp = r >> 1;
  return rp * 128 + ((((r & 1) << 6) | (gn << 4)) ^ ((rp & 7) << 4));
}

// ---- G: interleave U/W rows (row 2y=U[y], 2y+1=W[y]) -> bf16 swizzled slice-tiles
__global__ void cvt_g_kernel(const float* __restrict__ U, const float* __restrict__ W,
                             char* __restrict__ Gt) {
  int c = blockIdx.x * 256 + threadIdx.x;      // one 16B granule
  int g10 = c & 1023;
  int tile = c >> 10;                          // yblk*16 + ks
  int ks = tile & 15, yblk = tile >> 4;
  int r = g10 >> 2, gn = g10 & 3;
  int rg = yblk * 256 + r;
  int y = rg >> 1;
  uint4 o;
  if (y < NY) {
    const float* src = (rg & 1) ? W : U;
    const float4* p = (const float4*)(src + (size_t)y * ND + ks * BK + gn * 8);
    float4 f0 = p[0], f1 = p[1];
    o.x = pk2(f0.x, f0.y); o.y = pk2(f0.z, f0.w);
    o.z = pk2(f1.x, f1.y); o.w = pk2(f1.z, f1.w);
  } else {
    o = make_uint4(0u, 0u, 0u, 0u);
  }
  *(uint4*)(Gt + (size_t)tile * TILE + tile_off(r, gn)) = o;
}

// ---- x -> bf16 swizzled slice-tiles: [b 8][t 10][ks 16][16KB], zero-pad l>=2500
__global__ void cvt_x_kernel(const float* __restrict__ x, char* __restrict__ Xt) {
  int c = blockIdx.x * 256 + threadIdx.x;
  int g10 = c & 1023;
  int tile = c >> 10;
  int ks = tile & 15, rest = tile >> 4;
  int t = rest % NLT, b = rest / NLT;
  int r = g10 >> 2, gn = g10 & 3;
  int l = t * 256 + r;
  uint4 o;
  if (l < NL) {
    const float4* p = (const float4*)(x + ((size_t)b * NL + l) * ND + ks * BK + gn * 8);
    float4 f0 = p[0], f1 = p[1];
    o.x = pk2(f0.x, f0.y); o.y = pk2(f0.z, f0.w);
    o.z = pk2(f1.x, f1.y); o.w = pk2(f1.z, f1.w);
  } else {
    o = make_uint4(0u, 0u, 0u, 0u);
  }
  *(uint4*)(Xt + (size_t)tile * TILE + tile_off(r, gn)) = o;
}

// ---- fused dual-GEMM + deferred softmax; 512 thr = 8 waves (4M x 2N), 256x256 tile
// MFMA 32x32x16 (2495 TF rate vs 2176 for 16x16x32). Wave tile 64M x 128N:
// acc[2][4] f32x16 = 128 VGPR; per-lane label slots = 2mi x 8j = 16 (run 32 VGPR).
// C layout: col=lane&31, row=(reg&3)+8*(reg>>2)+4*(lane>>5); regs (2j,2j+1) are
// adjacent G rows = (s,t) of label jl[j]+2*hi. Schedule/staging = round 11 exact:
// 4 phases per K-tile (1 k-step of 16 each), read-ahead one phase, LGKM(6)/phase,
// stage 2 events/phase, VMC(2) publish at ph0/ph2 ends, never drain mid-loop.
template<int LSPL, int NSPL, bool PARTIAL>
__global__ __launch_bounds__(512, 2) void fused_kernel(
    const char* __restrict__ Gt, const char* __restrict__ Xt,
    const float* __restrict__ bias, float* __restrict__ out,
    float* __restrict__ PD, float* __restrict__ PN)
{
  __shared__ uint4 ring[8192];         // 128 KB: A bufs [0,64K), B bufs [64K,128K)
  char* ringC = (char*)ring;

  constexpr int NKT = LSPL * 8;        // K-tiles (K=64) per block

  const int tid  = threadIdx.x;
  const int lane = tid & 63;
  const int w    = tid >> 6;           // 0..7
  const int wrm  = w >> 1;             // 0..3  M-quarter (64 G-rows)
  const int wcn  = w & 1;              // 0..1  N-half (128 l)
  const int c32  = lane & 31;          // frag col/row index
  const int hi   = lane >> 5;          // k-granule half / label +2 selector

  const int id    = blockIdx.x;
  const int bb    = id & 7;            // batch, XCD-pinned
  const int n     = id >> 3;
  const int yblk  = n / NSPL;
  const int split = n - yblk * NSPL;
  const int tbase = split * LSPL;

  const char* GA = Gt + (size_t)yblk * NKS * TILE;
  const char* XB = Xt + ((size_t)bb * NLT + tbase) * NKS * TILE;

  f16v acc[2][4];
  float runD[2][8], runN[2][8];
  #pragma unroll
  for (int mi = 0; mi < 2; ++mi)
    #pragma unroll
    for (int j = 0; j < 8; ++j) { runD[mi][j] = 0.f; runN[mi][j] = 0.f; }

  // frag LDS offsets: E = k-step even (gn 0..1), O = odd (gn 2..3)
  int aoffE[2], aoffO[2], boffE[4], boffO[4];
  #pragma unroll
  for (int mi = 0; mi < 2; ++mi) {
    int r = wrm * 64 + mi * 32 + c32;
    aoffE[mi] = tile_off(r, hi);
    aoffO[mi] = tile_off(r, 2 + hi);
  }
  #pragma unroll
  for (int ni = 0; ni < 4; ++ni) {
    int r = wcn * 128 + ni * 32 + c32;
    boffE[ni] = tile_off(r, hi);
    boffO[ni] = tile_off(r, 2 + hi);
  }

  const int t16 = tid << 4;
  auto stgA = [&](int kt1, int par) {  // 2 vm-events/wave: A slice -> buf kt1&1
    const char* ga = GA + (size_t)((((kt1 & 7) << 1) | par)) * TILE;
    char* la = ringC + (kt1 & 1) * 32768 + par * 16384 + (w << 10);
    async_copy16(ga + t16, la);
    async_copy16(ga + 8192 + t16, la + 8192);
  };
  auto stgB = [&](int kt1, int par) {
    const char* gb = XB + (size_t)((kt1 >> 3) * 16 + ((kt1 & 7) << 1) + par) * TILE;
    char* lb = ringC + 65536 + (kt1 & 1) * 32768 + par * 16384 + (w << 10);
    async_copy16(gb + t16, lb);
    async_copy16(gb + 8192 + t16, lb + 8192);
  };

  auto softmax_acc = [&](int tt) {     // deferred: per-lane sums, no shuffles
    const int lb0 = (tbase + tt) * BN + wcn * 128 + c32;
    #pragma unroll
    for (int mi = 0; mi < 2; ++mi) {
      #pragma unroll
      for (int j = 0; j < 8; ++j) {
        float se = 0.f, ste = 0.f;
        #pragma unroll
        for (int ni = 0; ni < 4; ++ni) {
          bool valid = (lb0 + ni * 32) < NL;
          float sv = valid ? acc[mi][ni][2 * j] : -1e30f;
          float e = __expf(sv);
          se += e;
          ste += e * acc[mi][ni][2 * j + 1];
        }
        runD[mi][j] += se;
        runN[mi][j] += ste;
      }
    }
  };

#define SBAR __builtin_amdgcn_sched_barrier(0)
#define LGKM(N) asm volatile("s_waitcnt lgkmcnt(" #N ")" ::: "memory")
#define VMC(N)  asm volatile("s_waitcnt vmcnt(" #N ")" ::: "memory")

  // prologue: stage K-tile 0 fully (8 events); retire even half (vmcnt 4); publish
  stgA(0, 0); stgB(0, 0); stgA(0, 1); stgB(0, 1);
  VMC(4);
  __builtin_amdgcn_s_barrier();
  asm volatile("" ::: "memory");

  // frag sets X (even k-steps) / Y (odd); primer: s=0 frags of kt0 (buf0, par0, E)
  s8v afX[2], bvX[4], afY[2], bvY[4];
  #pragma unroll
  for (int mi = 0; mi < 2; ++mi) afX[mi] = *(const s8v*)(ringC + aoffE[mi]);
  #pragma unroll
  for (int ni = 0; ni < 4; ++ni) bvX[ni] = *(const s8v*)(ringC + 65536 + boffE[ni]);

  for (int kt = 0; kt < NKT; ++kt) {
    const int buf = kt & 1;
    const char* A0 = ringC + buf * 32768;            // par0 A
    const char* A1 = A0 + 16384;                     // par1 A
    const char* B0 = ringC + 65536 + buf * 32768;
    const char* B1 = B0 + 16384;
    const char* A0n = ringC + (buf ^ 1) * 32768;
    const char* B0n = ringC + 65536 + (buf ^ 1) * 32768;
    const bool hn = (kt + 1) < NKT;

    if ((kt & 7) == 0) {
      if (kt > 0) softmax_acc((kt >> 3) - 1);
      #pragma unroll
      for (int mi = 0; mi < 2; ++mi)
        #pragma unroll
        for (int ni = 0; ni < 4; ++ni)
          #pragma unroll
          for (int q = 0; q < 16; ++q) acc[mi][ni][q] = 0.f;
    }

    // ---- ph0: stage A0' | read s=1 frags (par0, O) -> MFMA s=0 (X) -> VMC -> bar
    if (hn) stgA(kt + 1, 0);
    #pragma unroll
    for (int mi = 0; mi < 2; ++mi) afY[mi] = *(const s8v*)(A0 + aoffO[mi]);
    #pragma unroll
    for (int ni = 0; ni < 4; ++ni) bvY[ni] = *(const s8v*)(B0 + boffO[ni]);
    SBAR;
    __builtin_amdgcn_s_barrier();
    LGKM(6); SBAR;
    __builtin_amdgcn_s_setprio(1);
    #pragma unroll
    for (int mi = 0; mi < 2; ++mi)
      #pragma unroll
      for (int ni = 0; ni < 4; ++ni)
        acc[mi][ni] = __builtin_amdgcn_mfma_f32_32x32x16_bf16(afX[mi], bvX[ni], acc[mi][ni], 0, 0, 0);
    __builtin_amdgcn_s_setprio(0);
    if (hn) { VMC(2); } else { VMC(0); }   // publish odd tiles of THIS K-tile
    SBAR;
    __builtin_amdgcn_s_barrier();
    asm volatile("" ::: "memory");

    // ---- ph1: stage B0' | read s=2 frags (par1, E) -> MFMA s=1 (Y) -> bar
    if (hn) stgB(kt + 1, 0);
    #pragma unroll
    for (int mi = 0; mi < 2; ++mi) afX[mi] = *(const s8v*)(A1 + aoffE[mi]);
    #pragma unroll
    for (int ni = 0; ni < 4; ++ni) bvX[ni] = *(const s8v*)(B1 + boffE[ni]);
    SBAR;
    __builtin_amdgcn_s_barrier();
    LGKM(6); SBAR;
    __builtin_amdgcn_s_setprio(1);
    #pragma unroll
    for (int mi = 0; mi < 2; ++mi)
      #pragma unroll
      for (int ni = 0; ni < 4; ++ni)
        acc[mi][ni] = __builtin_amdgcn_mfma_f32_32x32x16_bf16(afY[mi], bvY[ni], acc[mi][ni], 0, 0, 0);
    __builtin_amdgcn_s_setprio(0);
    SBAR;
    __builtin_amdgcn_s_barrier();
    asm volatile("" ::: "memory");

    // ---- ph2: stage A1' | read s=3 frags (par1, O) -> MFMA s=2 (X) -> VMC -> bar
    if (hn) stgA(kt + 1, 1);
    #pragma unroll
    for (int mi = 0; mi < 2; ++mi) afY[mi] = *(const s8v*)(A1 + aoffO[mi]);
    #pragma unroll
    for (int ni = 0; ni < 4; ++ni) bvY[ni] = *(const s8v*)(B1 + boffO[ni]);
    SBAR;
    __builtin_amdgcn_s_barrier();
    LGKM(6); SBAR;
    __builtin_amdgcn_s_setprio(1);
    #pragma unroll
    for (int mi = 0; mi < 2; ++mi)
      #pragma unroll
      for (int ni = 0; ni < 4; ++ni)
        acc[mi][ni] = __builtin_amdgcn_mfma_f32_32x32x16_bf16(afX[mi], bvX[ni], acc[mi][ni], 0, 0, 0);
    __builtin_amdgcn_s_setprio(0);
    if (hn) VMC(2);                        // publish even tiles of NEXT K-tile
    SBAR;
    __builtin_amdgcn_s_barrier();
    asm volatile("" ::: "memory");

    // ---- ph3: stage B1' | read next s=0 frags (buf^1, par0, E) -> MFMA s=3 (Y) -> bar
    if (hn) {
      stgB(kt + 1, 1);
      #pragma unroll
      for (int mi = 0; mi < 2; ++mi) afX[mi] = *(const s8v*)(A0n + aoffE[mi]);
      #pragma unroll
      for (int ni = 0; ni < 4; ++ni) bvX[ni] = *(const s8v*)(B0n + boffE[ni]);
      SBAR;
      __builtin_amdgcn_s_barrier();
      LGKM(6); SBAR;
    } else {
      SBAR;
      __builtin_amdgcn_s_barrier();
      LGKM(0); SBAR;
    }
    __builtin_amdgcn_s_setprio(1);
    #pragma unroll
    for (int mi = 0; mi < 2; ++mi)
      #pragma unroll
      for (int ni = 0; ni < 4; ++ni)
        acc[mi][ni] = __builtin_amdgcn_mfma_f32_32x32x16_bf16(afY[mi], bvY[ni], acc[mi][ni], 0, 0, 0);
    __builtin_amdgcn_s_setprio(0);
    SBAR;
    __builtin_amdgcn_s_barrier();
    asm volatile("" ::: "memory");
  }
  softmax_acc(LSPL - 1);

#undef SBAR
#undef LGKM
#undef VMC

  // ---- once-per-kernel: 32-col reduce (xor 1..16 stays within each 32-lane half)
  #pragma unroll
  for (int mi = 0; mi < 2; ++mi)
    #pragma unroll
    for (int j = 0; j < 8; ++j) {
      float d = runD[mi][j], nn = runN[mi][j];
      #pragma unroll
      for (int off = 1; off < 32; off <<= 1) {
        d += __shfl_xor(d, off);
        nn += __shfl_xor(nn, off);
      }
      runD[mi][j] = d; runN[mi][j] = nn;
    }

  // ---- 2-way wcn merge via LDS (plain sums), then write partials / output
  const int jl[8] = {0, 1, 4, 5, 8, 9, 12, 13};
  __syncthreads();
  float* sm = (float*)ring;      // 128 labels x 2 wcn x 2 floats = 2 KB
  if (c32 == 0) {                // lanes 0 (hi=0) and 32 (hi=1)
    #pragma unroll
    for (int mi = 0; mi < 2; ++mi)
      #pragma unroll
      for (int j = 0; j < 8; ++j) {
        int lab = wrm * 32 + mi * 16 + jl[j] + 2 * hi;   // 0..127
        float* s2 = sm + (lab * 2 + wcn) * 2;
        s2[0] = runD[mi][j]; s2[1] = runN[mi][j];
      }
  }
  __syncthreads();
  if (tid < 128) {
    float D = 0.f, N = 0.f;
    #pragma unroll
    for (int q = 0; q < 2; ++q) {
      const float* s2 = sm + (tid * 2 + q) * 2;
      D += s2[0]; N += s2[1];
    }
    int y = yblk * 128 + tid;
    if constexpr (PARTIAL) {
      size_t o = ((size_t)split * NB + bb) * YPAD + y;
      PD[o] = D; PN[o] = N;
    } else {
      if (y < NY) out[(size_t)bb * NY + y] = N / D + bias[y];
    }
  }
}

// ---- merge SPLIT partials + bias -> out (plain sums)
__global__ void merge_kernel(const float* __restrict__ PD, const float* __restrict__ PN,
                             const float* __restrict__ bias, float* __restrict__ out) {
  int idx = blockIdx.x * 256 + threadIdx.x;      // NB*YPAD
  int b = idx / YPAD, y = idx - b * YPAD;
  if (y >= NY) return;
  float D = 0.f, N = 0.f;
  #pragma unroll
  for (int s = 0; s < SPLIT; ++s) {
    size_t o = ((size_t)s * NB + b) * YPAD + y;
    D += PD[o];
    N += PN[o];
  }
  out[(size_t)b * NY + y] = N / D + bias[y];
}

extern "C" void kernel_launch(void* const* d_in, const int* in_sizes, int n_in,
                              void* d_out, int out_size, void* d_ws, size_t ws_size,
                              hipStream_t stream) {
  const float* xf   = (const float*)d_in[0];
  const float* Uf   = (const float*)d_in[1];
  const float* Wf   = (const float*)d_in[2];
  const float* bias = (const float*)d_in[3];
  float* out = (float*)d_out;

  char* Gt = (char*)d_ws;
  char* Xt = Gt + GT_BYTES;
  float* PD = (float*)(Xt + XT_BYTES);
  float* PN = PD + P_ELEMS;

  // G granules: 1,146,880 / 256 = 4480 blocks ; X granules: 1,310,720 / 256 = 5120
  cvt_g_kernel<<<4480, 256, 0, stream>>>(Uf, Wf, Gt);
  cvt_x_kernel<<<5120, 256, 0, stream>>>(xf, Xt);

  const size_t need_main = GT_BYTES + XT_BYTES + 2 * P_BYTES;   // ~42.2 MB
  if (ws_size >= need_main) {
    fused_kernel<LSPL_MAIN, SPLIT, true><<<NYB * NB * SPLIT, 512, 0, stream>>>(
        Gt, Xt, bias, out, PD, PN);
    merge_kernel<<<NB * YPAD / 256, 256, 0, stream>>>(PD, PN, bias, out);
  } else {
    fused_kernel<NLT, 1, false><<<NYB * NB, 512, 0, stream>>>(
        Gt, Xt, bias, out, PD, PN);
  }
}

// Round 13
// 393.814 us; speedup vs baseline: 1.0386x; 1.0386x over previous
//
#include <hip/hip_runtime.h>
#include <hip/hip_bf16.h>

// Problem constants
#define NB 8
#define NL 2500
#define ND 512
#define NY 8921

// Tiling
#define BM 256             // G rows per block (128 labels, U/W interleaved)
#define BN 256             // l-tile
#define BK 32              // k-slice per LDS tile (2 tiles per K-tile of 64)
#define NKS 16             // slices per l-tile
#define LPAD 2560          // 10 * 256
#define NLT 10             // LPAD/BN
#define NYB 70             // ceil(NY/128)
#define YPAD 8960          // NYB*128

#define SPLIT 5            // l-range splits (2 l-tiles per block)
#define LSPL_MAIN 2

#define TILE 16384         // 256 rows x 32 bf16, lane-linear blocked layout
#define GT_BYTES ((size_t)NYB * NKS * TILE)              // 18,350,080
#define XT_BYTES ((size_t)NB * NLT * NKS * TILE)         // 20,971,520
#define P_ELEMS  ((size_t)SPLIT * NB * YPAD)             // 358,400
#define P_BYTES  (P_ELEMS * 4)

typedef short s8v  __attribute__((ext_vector_type(8)));
typedef float f16v __attribute__((ext_vector_type(16)));

__device__ __forceinline__ unsigned short f2bf(float f) {
  unsigned int u = __float_as_uint(f);
  return (unsigned short)((u + 0x7FFFu + ((u >> 16) & 1u)) >> 16);
}
__device__ __forceinline__ unsigned int pk2(float a, float b) {
  return (unsigned int)f2bf(a) | ((unsigned int)f2bf(b) << 16);
}
__device__ __forceinline__ void async_copy16(const char* g, char* l) {
  __builtin_amdgcn_global_load_lds(
      (const __attribute__((address_space(1))) void*)g,
      (__attribute__((address_space(3))) void*)l, 16, 0, 0);
}

// Lane-linear blocked tile layout for the 32x32 MFMA read pattern:
// slot(r,gn) = (r>>5)<<7 | (gn>>1)<<6 | (gn&1)<<5 | (r&31);  byte = slot*16.
// A wave's frag read (rows base..base+31, gn pair) is base + lane*16 —
// identical address pattern to the global_load_lds staging write -> conflict-free.

// ---- G: interleave U/W rows (row 2y=U[y], 2y+1=W[y]) -> bf16 tiles (new layout)
__global__ void cvt_g_kernel(const float* __restrict__ U, const float* __restrict__ W,
                             char* __restrict__ Gt) {
  int c = blockIdx.x * 256 + threadIdx.x;      // one 16B output slot
  int s = c & 1023;                            // slot within tile
  int tile = c >> 10;                          // yblk*16 + ks
  int ks = tile & 15, yblk = tile >> 4;
  int r  = ((s >> 7) << 5) | (s & 31);         // inverse slot map
  int gn = (((s >> 6) & 1) << 1) | ((s >> 5) & 1);
  int rg = yblk * 256 + r;
  int y = rg >> 1;
  uint4 o;
  if (y < NY) {
    const float* src = (rg & 1) ? W : U;
    const float4* p = (const float4*)(src + (size_t)y * ND + ks * BK + gn * 8);
    float4 f0 = p[0], f1 = p[1];
    o.x = pk2(f0.x, f0.y); o.y = pk2(f0.z, f0.w);
    o.z = pk2(f1.x, f1.y); o.w = pk2(f1.z, f1.w);
  } else {
    o = make_uint4(0u, 0u, 0u, 0u);
  }
  *(uint4*)(Gt + (size_t)c * 16) = o;          // linear coalesced store
}

// ---- x -> bf16 tiles (new layout): [b 8][t 10][ks 16][16KB], zero-pad l>=2500
__global__ void cvt_x_kernel(const float* __restrict__ x, char* __restrict__ Xt) {
  int c = blockIdx.x * 256 + threadIdx.x;
  int s = c & 1023;
  int tile = c >> 10;
  int ks = tile & 15, rest = tile >> 4;
  int t = rest % NLT, b = rest / NLT;
  int r  = ((s >> 7) << 5) | (s & 31);
  int gn = (((s >> 6) & 1) << 1) | ((s >> 5) & 1);
  int l = t * 256 + r;
  uint4 o;
  if (l < NL) {
    const float4* p = (const float4*)(x + ((size_t)b * NL + l) * ND + ks * BK + gn * 8);
    float4 f0 = p[0], f1 = p[1];
    o.x = pk2(f0.x, f0.y); o.y = pk2(f0.z, f0.w);
    o.z = pk2(f1.x, f1.y); o.w = pk2(f1.z, f1.w);
  } else {
    o = make_uint4(0u, 0u, 0u, 0u);
  }
  *(uint4*)(Xt + (size_t)c * 16) = o;
}

// ---- fused dual-GEMM + deferred softmax; 512 thr = 8 waves (4M x 2N), 256x256 tile
// MFMA 32x32x16; wave tile 64M x 128N; schedule = round 11/12 exact
// (4 phases/K-tile, read-ahead one phase, LGKM(6), VMC(2) publishes, never drain).
template<int LSPL, int NSPL, bool PARTIAL>
__global__ __launch_bounds__(512, 2) void fused_kernel(
    const char* __restrict__ Gt, const char* __restrict__ Xt,
    const float* __restrict__ bias, float* __restrict__ out,
    float* __restrict__ PD, float* __restrict__ PN)
{
  __shared__ uint4 ring[8192];         // 128 KB: A bufs [0,64K), B bufs [64K,128K)
  char* ringC = (char*)ring;

  constexpr int NKT = LSPL * 8;        // K-tiles (K=64) per block

  const int tid  = threadIdx.x;
  const int lane = tid & 63;
  const int w    = tid >> 6;           // 0..7
  const int wrm  = w >> 1;             // 0..3  M-quarter (64 G-rows)
  const int wcn  = w & 1;              // 0..1  N-half (128 l)
  const int c32  = lane & 31;          // frag col/row index
  const int hi   = lane >> 5;          // k-granule half / label +2 selector

  const int id    = blockIdx.x;
  const int bb    = id & 7;            // batch, XCD-pinned
  const int n     = id >> 3;
  const int yblk  = n / NSPL;
  const int split = n - yblk * NSPL;
  const int tbase = split * LSPL;

  const char* GA = Gt + (size_t)yblk * NKS * TILE;
  const char* XB = Xt + ((size_t)bb * NLT + tbase) * NKS * TILE;

  f16v acc[2][4];
  float runD[2][8], runN[2][8];
  #pragma unroll
  for (int mi = 0; mi < 2; ++mi)
    #pragma unroll
    for (int j = 0; j < 8; ++j) { runD[mi][j] = 0.f; runN[mi][j] = 0.f; }

  // frag LDS offsets (lane-linear layout): blk*2048 + par*1024 + hi*512 + c32*16
  const int lin = hi * 512 + c32 * 16;
  int aoffE[2], aoffO[2], boffE[4], boffO[4];
  #pragma unroll
  for (int mi = 0; mi < 2; ++mi) {
    int blk = wrm * 2 + mi;
    aoffE[mi] = blk * 2048 + lin;
    aoffO[mi] = blk * 2048 + 1024 + lin;
  }
  #pragma unroll
  for (int ni = 0; ni < 4; ++ni) {
    int blk = wcn * 4 + ni;
    boffE[ni] = blk * 2048 + lin;
    boffO[ni] = blk * 2048 + 1024 + lin;
  }

  const int t16 = tid << 4;
  auto stgA = [&](int kt1, int par) {  // 2 vm-events/wave: A slice -> buf kt1&1
    const char* ga = GA + (size_t)((((kt1 & 7) << 1) | par)) * TILE;
    char* la = ringC + (kt1 & 1) * 32768 + par * 16384 + (w << 10);
    async_copy16(ga + t16, la);
    async_copy16(ga + 8192 + t16, la + 8192);
  };
  auto stgB = [&](int kt1, int par) {
    const char* gb = XB + (size_t)((kt1 >> 3) * 16 + ((kt1 & 7) << 1) + par) * TILE;
    char* lb = ringC + 65536 + (kt1 & 1) * 32768 + par * 16384 + (w << 10);
    async_copy16(gb + t16, lb);
    async_copy16(gb + 8192 + t16, lb + 8192);
  };

  auto softmax_acc = [&](int tt) {     // deferred: per-lane sums, no shuffles
    const int lb0 = (tbase + tt) * BN + wcn * 128 + c32;
    #pragma unroll
    for (int mi = 0; mi < 2; ++mi) {
      #pragma unroll
      for (int j = 0; j < 8; ++j) {
        float se = 0.f, ste = 0.f;
        #pragma unroll
        for (int ni = 0; ni < 4; ++ni) {
          bool valid = (lb0 + ni * 32) < NL;
          float sv = valid ? acc[mi][ni][2 * j] : -1e30f;
          float e = __expf(sv);
          se += e;
          ste += e * acc[mi][ni][2 * j + 1];
        }
        runD[mi][j] += se;
        runN[mi][j] += ste;
      }
    }
  };

#define SBAR __builtin_amdgcn_sched_barrier(0)
#define LGKM(N) asm volatile("s_waitcnt lgkmcnt(" #N ")" ::: "memory")
#define VMC(N)  asm volatile("s_waitcnt vmcnt(" #N ")" ::: "memory")

  // prologue: stage K-tile 0 fully (8 events); retire even half (vmcnt 4); publish
  stgA(0, 0); stgB(0, 0); stgA(0, 1); stgB(0, 1);
  VMC(4);
  __builtin_amdgcn_s_barrier();
  asm volatile("" ::: "memory");

  // frag sets X (even k-steps) / Y (odd); primer: s=0 frags of kt0 (buf0, par0, E)
  s8v afX[2], bvX[4], afY[2], bvY[4];
  #pragma unroll
  for (int mi = 0; mi < 2; ++mi) afX[mi] = *(const s8v*)(ringC + aoffE[mi]);
  #pragma unroll
  for (int ni = 0; ni < 4; ++ni) bvX[ni] = *(const s8v*)(ringC + 65536 + boffE[ni]);

  for (int kt = 0; kt < NKT; ++kt) {
    const int buf = kt & 1;
    const char* A0 = ringC + buf * 32768;            // par0 A
    const char* A1 = A0 + 16384;                     // par1 A
    const char* B0 = ringC + 65536 + buf * 32768;
    const char* B1 = B0 + 16384;
    const char* A0n = ringC + (buf ^ 1) * 32768;
    const char* B0n = ringC + 65536 + (buf ^ 1) * 32768;
    const bool hn = (kt + 1) < NKT;

    if ((kt & 7) == 0) {
      if (kt > 0) softmax_acc((kt >> 3) - 1);
      #pragma unroll
      for (int mi = 0; mi < 2; ++mi)
        #pragma unroll
        for (int ni = 0; ni < 4; ++ni)
          #pragma unroll
          for (int q = 0; q < 16; ++q) acc[mi][ni][q] = 0.f;
    }

    // ---- ph0: stage A0' | read s=1 frags (par0, O) -> MFMA s=0 (X) -> VMC -> bar
    if (hn) stgA(kt + 1, 0);
    #pragma unroll
    for (int mi = 0; mi < 2; ++mi) afY[mi] = *(const s8v*)(A0 + aoffO[mi]);
    #pragma unroll
    for (int ni = 0; ni < 4; ++ni) bvY[ni] = *(const s8v*)(B0 + boffO[ni]);
    SBAR;
    __builtin_amdgcn_s_barrier();
    LGKM(6); SBAR;
    __builtin_amdgcn_s_setprio(1);
    #pragma unroll
    for (int mi = 0; mi < 2; ++mi)
      #pragma unroll
      for (int ni = 0; ni < 4; ++ni)
        acc[mi][ni] = __builtin_amdgcn_mfma_f32_32x32x16_bf16(afX[mi], bvX[ni], acc[mi][ni], 0, 0, 0);
    __builtin_amdgcn_s_setprio(0);
    if (hn) { VMC(2); } else { VMC(0); }   // publish odd tiles of THIS K-tile
    SBAR;
    __builtin_amdgcn_s_barrier();
    asm volatile("" ::: "memory");

    // ---- ph1: stage B0' | read s=2 frags (par1, E) -> MFMA s=1 (Y) -> bar
    if (hn) stgB(kt + 1, 0);
    #pragma unroll
    for (int mi = 0; mi < 2; ++mi) afX[mi] = *(const s8v*)(A1 + aoffE[mi]);
    #pragma unroll
    for (int ni = 0; ni < 4; ++ni) bvX[ni] = *(const s8v*)(B1 + boffE[ni]);
    SBAR;
    __builtin_amdgcn_s_barrier();
    LGKM(6); SBAR;
    __builtin_amdgcn_s_setprio(1);
    #pragma unroll
    for (int mi = 0; mi < 2; ++mi)
      #pragma unroll
      for (int ni = 0; ni < 4; ++ni)
        acc[mi][ni] = __builtin_amdgcn_mfma_f32_32x32x16_bf16(afY[mi], bvY[ni], acc[mi][ni], 0, 0, 0);
    __builtin_amdgcn_s_setprio(0);
    SBAR;
    __builtin_amdgcn_s_barrier();
    asm volatile("" ::: "memory");

    // ---- ph2: stage A1' | read s=3 frags (par1, O) -> MFMA s=2 (X) -> VMC -> bar
    if (hn) stgA(kt + 1, 1);
    #pragma unroll
    for (int mi = 0; mi < 2; ++mi) afY[mi] = *(const s8v*)(A1 + aoffO[mi]);
    #pragma unroll
    for (int ni = 0; ni < 4; ++ni) bvY[ni] = *(const s8v*)(B1 + boffO[ni]);
    SBAR;
    __builtin_amdgcn_s_barrier();
    LGKM(6); SBAR;
    __builtin_amdgcn_s_setprio(1);
    #pragma unroll
    for (int mi = 0; mi < 2; ++mi)
      #pragma unroll
      for (int ni = 0; ni < 4; ++ni)
        acc[mi][ni] = __builtin_amdgcn_mfma_f32_32x32x16_bf16(afX[mi], bvX[ni], acc[mi][ni], 0, 0, 0);
    __builtin_amdgcn_s_setprio(0);
    if (hn) VMC(2);                        // publish even tiles of NEXT K-tile
    SBAR;
    __builtin_amdgcn_s_barrier();
    asm volatile("" ::: "memory");

    // ---- ph3: stage B1' | read next s=0 frags (buf^1, par0, E) -> MFMA s=3 (Y) -> bar
    if (hn) {
      stgB(kt + 1, 1);
      #pragma unroll
      for (int mi = 0; mi < 2; ++mi) afX[mi] = *(const s8v*)(A0n + aoffE[mi]);
      #pragma unroll
      for (int ni = 0; ni < 4; ++ni) bvX[ni] = *(const s8v*)(B0n + boffE[ni]);
      SBAR;
      __builtin_amdgcn_s_barrier();
      LGKM(6); SBAR;
    } else {
      SBAR;
      __builtin_amdgcn_s_barrier();
      LGKM(0); SBAR;
    }
    __builtin_amdgcn_s_setprio(1);
    #pragma unroll
    for (int mi = 0; mi < 2; ++mi)
      #pragma unroll
      for (int ni = 0; ni < 4; ++ni)
        acc[mi][ni] = __builtin_amdgcn_mfma_f32_32x32x16_bf16(afY[mi], bvY[ni], acc[mi][ni], 0, 0, 0);
    __builtin_amdgcn_s_setprio(0);
    SBAR;
    __builtin_amdgcn_s_barrier();
    asm volatile("" ::: "memory");
  }
  softmax_acc(LSPL - 1);

#undef SBAR
#undef LGKM
#undef VMC

  // ---- once-per-kernel: 32-col reduce (xor 1..16 stays within each 32-lane half)
  #pragma unroll
  for (int mi = 0; mi < 2; ++mi)
    #pragma unroll
    for (int j = 0; j < 8; ++j) {
      float d = runD[mi][j], nn = runN[mi][j];
      #pragma unroll
      for (int off = 1; off < 32; off <<= 1) {
        d += __shfl_xor(d, off);
        nn += __shfl_xor(nn, off);
      }
      runD[mi][j] = d; runN[mi][j] = nn;
    }

  // ---- 2-way wcn merge via LDS (plain sums), then write partials / output
  const int jl[8] = {0, 1, 4, 5, 8, 9, 12, 13};
  __syncthreads();
  float* sm = (float*)ring;      // 128 labels x 2 wcn x 2 floats = 2 KB
  if (c32 == 0) {                // lanes 0 (hi=0) and 32 (hi=1)
    #pragma unroll
    for (int mi = 0; mi < 2; ++mi)
      #pragma unroll
      for (int j = 0; j < 8; ++j) {
        int lab = wrm * 32 + mi * 16 + jl[j] + 2 * hi;   // 0..127
        float* s2 = sm + (lab * 2 + wcn) * 2;
        s2[0] = runD[mi][j]; s2[1] = runN[mi][j];
      }
  }
  __syncthreads();
  if (tid < 128) {
    float D = 0.f, N = 0.f;
    #pragma unroll
    for (int q = 0; q < 2; ++q) {
      const float* s2 = sm + (tid * 2 + q) * 2;
      D += s2[0]; N += s2[1];
    }
    int y = yblk * 128 + tid;
    if constexpr (PARTIAL) {
      size_t o = ((size_t)split * NB + bb) * YPAD + y;
      PD[o] = D; PN[o] = N;
    } else {
      if (y < NY) out[(size_t)bb * NY + y] = N / D + bias[y];
    }
  }
}

// ---- merge SPLIT partials + bias -> out (plain sums)
__global__ void merge_kernel(const float* __restrict__ PD, const float* __restrict__ PN,
                             const float* __restrict__ bias, float* __restrict__ out) {
  int idx = blockIdx.x * 256 + threadIdx.x;      // NB*YPAD
  int b = idx / YPAD, y = idx - b * YPAD;
  if (y >= NY) return;
  float D = 0.f, N = 0.f;
  #pragma unroll
  for (int s = 0; s < SPLIT; ++s) {
    size_t o = ((size_t)s * NB + b) * YPAD + y;
    D += PD[o];
    N += PN[o];
  }
  out[(size_t)b * NY + y] = N / D + bias[y];
}

extern "C" void kernel_launch(void* const* d_in, const int* in_sizes, int n_in,
                              void* d_out, int out_size, void* d_ws, size_t ws_size,
                              hipStream_t stream) {
  const float* xf   = (const float*)d_in[0];
  const float* Uf   = (const float*)d_in[1];
  const float* Wf   = (const float*)d_in[2];
  const float* bias = (const float*)d_in[3];
  float* out = (float*)d_out;

  char* Gt = (char*)d_ws;
  char* Xt = Gt + GT_BYTES;
  float* PD = (float*)(Xt + XT_BYTES);
  float* PN = PD + P_ELEMS;

  // G granules: 1,146,880 / 256 = 4480 blocks ; X granules: 1,310,720 / 256 = 5120
  cvt_g_kernel<<<4480, 256, 0, stream>>>(Uf, Wf, Gt);
  cvt_x_kernel<<<5120, 256, 0, stream>>>(xf, Xt);

  const size_t need_main = GT_BYTES + XT_BYTES + 2 * P_BYTES;   // ~42.2 MB
  if (ws_size >= need_main) {
    fused_kernel<LSPL_MAIN, SPLIT, true><<<NYB * NB * SPLIT, 512, 0, stream>>>(
        Gt, Xt, bias, out, PD, PN);
    merge_kernel<<<NB * YPAD / 256, 256, 0, stream>>>(PD, PN, bias, out);
  } else {
    fused_kernel<NLT, 1, false><<<NYB * NB, 512, 0, stream>>>(
        Gt, Xt, bias, out, PD, PN);
  }
}